// Round 7
// baseline (96.113 us; speedup 1.0000x reference)
//
#include <hip/hip_runtime.h>
#include <hip/hip_bf16.h>

typedef unsigned int uint;
typedef unsigned short ushort;

// Dims
#define Bn 16
#define Dd 256
#define Nn 4096
#define Hh 4
#define Kk 16
#define Vv 64
#define Rr 23
#define NCH 240   // 64 q + 16 k + 64 v + 92 g + 4 pad
#define NRT 15    // 240/16 row-tiles

typedef short bf16x8s __attribute__((ext_vector_type(8)));
typedef float f32x4 __attribute__((ext_vector_type(4)));

static __device__ __forceinline__ ushort f2bf(float f) {
    __hip_bfloat16 h = __float2bfloat16(f);
    return __builtin_bit_cast(ushort, h);
}
static __device__ __forceinline__ float bf2f(ushort u) {
    return __uint_as_float(((uint)u) << 16);
}
static __device__ __forceinline__ float bflo(uint u) { return __uint_as_float(u << 16); }
static __device__ __forceinline__ float bfhi(uint u) { return __uint_as_float(u & 0xffff0000u); }

// ---------------- Kernel 1: pack 240 BN-folded rows (bf16, A-fragment order) ----------------
// rows: 0..63 q (BN), 64..79 k, 80..143 v (BN), 144..235 g = conv_w-combined q rows, 236..239 zero
__global__ __launch_bounds__(256) void pack_kernel(
    const float* __restrict__ Wq, const float* __restrict__ qg, const float* __restrict__ qb,
    const float* __restrict__ qm, const float* __restrict__ qv,
    const float* __restrict__ Wk, const float* __restrict__ Wv,
    const float* __restrict__ vg, const float* __restrict__ vb,
    const float* __restrict__ vm, const float* __restrict__ vvar,
    const float* __restrict__ conv_w,
    ushort* __restrict__ Wf16, float* __restrict__ bias) {
    int c = blockIdx.x;       // 0..239
    int d = threadIdx.x;      // 0..255
    float wval = 0.f, bs = 0.f;
    if (c < 64) {
        float scale = qg[c] * rsqrtf(qv[c] + 1e-5f);
        bs = qb[c] - qm[c] * scale;
        wval = Wq[c * Dd + d] * scale;
    } else if (c < 80) {
        wval = Wk[(c - 64) * Dd + d];
    } else if (c < 144) {
        int j = c - 80;
        float scale = vg[j] * rsqrtf(vvar[j] + 1e-5f);
        bs = vb[j] - vm[j] * scale;
        wval = Wv[j * Dd + d] * scale;
    } else if (c < 236) {
        int cg = c - 144;
        int h = cg / 23, r = cg - h * 23;
        float wsum = 0.f, bsum = 0.f;
        for (int k = 0; k < 16; k++) {
            int qc = h * 16 + k;
            float scale = qg[qc] * rsqrtf(qv[qc] + 1e-5f);
            float cw = conv_w[k * Rr + r];
            wsum += cw * (Wq[qc * Dd + d] * scale);
            bsum += cw * (qb[qc] - qm[qc] * scale);
        }
        wval = wsum; bs = bsum;
    }
    int rt = c >> 4, lm = c & 15;
    int kk = d >> 5, hi = (d >> 3) & 3, j = d & 7;
    Wf16[((rt * 8 + kk) * 64 + hi * 16 + lm) * 8 + j] = f2bf(wval);
    if (d == 0) bias[c] = bs;
}

// ---------------- Kernel 2: MFMA projection -> 4 consumer-layout buffers ----------------
__global__ __launch_bounds__(256, 4) void proj_mfma_kernel(
    const float* __restrict__ x, const ushort* __restrict__ Wf16,
    const float* __restrict__ bias,
    ushort* __restrict__ qbufT, float* __restrict__ kbuf,
    ushort* __restrict__ vbufT, ushort* __restrict__ gbuf) {
    __shared__ ushort Wlds[NRT * 2 * 64 * 8];   // 30720 B (2 k-steps per phase)

    int b = blockIdx.y;
    int n0 = blockIdx.x * 64;
    int t = threadIdx.x;
    int w = t >> 6, l = t & 63;
    int lm = l & 15, hi = l >> 4;
    int n = n0 + w * 16 + lm;     // this lane's output column

    const uint* WfU = (const uint*)Wf16;
    uint* WldsU = (uint*)Wlds;

    f32x4 acc[NRT];
#pragma unroll
    for (int rt = 0; rt < NRT; rt++) acc[rt] = (f32x4){0.f, 0.f, 0.f, 0.f};

    const float* xb = x + (size_t)b * Dd * Nn + n;

    for (int p = 0; p < 4; p++) {
        int kb = p * 2;
        if (p) __syncthreads();
#pragma unroll
        for (int i = 0; i < 30; i++) {
            int flat = t + 256 * i;
            int f2 = flat >> 8;          // rt*2 + kkl
            int rt = f2 >> 1, kkl = f2 & 1;
            WldsU[flat] = WfU[((rt * 8 + kb + kkl) << 8) + (flat & 255)];
        }
        __syncthreads();
#pragma unroll
        for (int kkl = 0; kkl < 2; kkl++) {
            int kk = kb + kkl;
            const float* xp = xb + (size_t)(kk * 32 + hi * 8) * Nn;
            float f[8];
#pragma unroll
            for (int j = 0; j < 8; j++) f[j] = xp[(size_t)j * Nn];
            bf16x8s bfrag;
#pragma unroll
            for (int j = 0; j < 8; j++) bfrag[j] = (short)f2bf(f[j]);
#pragma unroll
            for (int rt = 0; rt < NRT; rt++) {
                bf16x8s afrag = *reinterpret_cast<const bf16x8s*>(
                    &Wlds[(size_t)((rt * 2 + kkl) * 64 + l) * 8]);
                acc[rt] = __builtin_amdgcn_mfma_f32_16x16x32_bf16(afrag, bfrag, acc[rt], 0, 0, 0);
            }
        }
    }

    // ---- epilogue: consumer layouts ----
    // q rows 0..63 -> qbufT[b][n][k*4+h] bf16 (k = hi*4+rr, h = rt)
#pragma unroll
    for (int rt = 0; rt < 4; rt++) {
#pragma unroll
        for (int rr = 0; rr < 4; rr++) {
            int c = rt * 16 + hi * 4 + rr;
            float val = acc[rt][rr] + bias[c];
            int pos = (hi * 4 + rr) * 4 + rt;
            qbufT[((size_t)b * Nn + n) * 64 + pos] = f2bf(val);
        }
    }
    // k rows 64..79 -> kbuf[b][kc][n] fp32
#pragma unroll
    for (int rr = 0; rr < 4; rr++) {
        int kc = hi * 4 + rr;
        kbuf[((size_t)b * 16 + kc) * Nn + n] = acc[4][rr] + bias[64 + kc];
    }
    // v rows 80..143 -> vbufT[b][n][v] bf16 (packed ushort4)
#pragma unroll
    for (int rt = 5; rt < 9; rt++) {
        int v0 = (rt - 5) * 16 + hi * 4;
        ushort4 pk;
        pk.x = f2bf(acc[rt][0] + bias[80 + v0 + 0]);
        pk.y = f2bf(acc[rt][1] + bias[80 + v0 + 1]);
        pk.z = f2bf(acc[rt][2] + bias[80 + v0 + 2]);
        pk.w = f2bf(acc[rt][3] + bias[80 + v0 + 3]);
        *reinterpret_cast<ushort4*>(&vbufT[((size_t)b * Nn + n) * 64 + v0]) = pk;
    }
    // g rows 144..235 -> gbuf[b][r][n][h] bf16
#pragma unroll
    for (int rt = 9; rt < 15; rt++) {
#pragma unroll
        for (int rr = 0; rr < 4; rr++) {
            int cg = rt * 16 + hi * 4 + rr - 144;
            if (cg < 92) {
                int h = (cg * 713) >> 14;      // floor(cg/23), exact for 0..91
                int r = cg - h * 23;
                float val = acc[rt][rr] + bias[144 + cg];
                gbuf[(((size_t)b * Rr + r) * Nn + n) * 4 + h] = f2bf(val);
            }
        }
    }
}

// ---------------- Kernel 3: softmax over n for k channels (kbuf) ----------------
__global__ __launch_bounds__(256) void softmax_kernel(float* __restrict__ kbuf) {
    int b = blockIdx.y, kc = blockIdx.x;
    float* row = kbuf + ((size_t)b * 16 + kc) * Nn;
    int t = threadIdx.x;
    float vals[16];
    float m = -1e30f;
#pragma unroll
    for (int i = 0; i < 16; i++) {
        vals[i] = row[t + 256 * i];
        m = fmaxf(m, vals[i]);
    }
#pragma unroll
    for (int off = 32; off; off >>= 1) m = fmaxf(m, __shfl_xor(m, off));
    __shared__ float sm[4], ss[4];
    int wave = t >> 6;
    if ((t & 63) == 0) sm[wave] = m;
    __syncthreads();
    m = fmaxf(fmaxf(sm[0], sm[1]), fmaxf(sm[2], sm[3]));
    float s = 0.f;
#pragma unroll
    for (int i = 0; i < 16; i++) {
        vals[i] = __expf(vals[i] - m);
        s += vals[i];
    }
#pragma unroll
    for (int off = 32; off; off >>= 1) s += __shfl_xor(s, off);
    if ((t & 63) == 0) ss[wave] = s;
    __syncthreads();
    s = ss[0] + ss[1] + ss[2] + ss[3];
    float inv = 1.f / s;
#pragma unroll
    for (int i = 0; i < 16; i++) row[t + 256 * i] = vals[i] * inv;
}

// ---------------- Kernel 4: lam_c[b][16][64] = sum_n kk*vv ----------------
#define NCHUNK 128
__global__ __launch_bounds__(256) void lamc_kernel(
    const float* __restrict__ kbuf, const ushort* __restrict__ vbufT,
    float* __restrict__ lam) {
    int b = blockIdx.y;
    int n0 = blockIdx.x * NCHUNK;
    __shared__ float kks[Kk][NCHUNK + 1];   // 8256 B
    __shared__ ushort vvT[NCHUNK][72];      // 18432 B, rows 144 B
    int t = threadIdx.x;
    // stage kk: 512 float4
#pragma unroll
    for (int m = 0; m < 2; m++) {
        int i = t + 256 * m;
        int r = i >> 5, seg = i & 31;
        float4 f = *reinterpret_cast<const float4*>(&kbuf[((size_t)b * 16 + r) * Nn + n0 + seg * 4]);
        kks[r][seg * 4 + 0] = f.x;
        kks[r][seg * 4 + 1] = f.y;
        kks[r][seg * 4 + 2] = f.z;
        kks[r][seg * 4 + 3] = f.w;
    }
    // stage vvT: 128 rows x 8 uint4 (linear)
#pragma unroll
    for (int m = 0; m < 4; m++) {
        int i = t + 256 * m;
        int row = i >> 3, seg = i & 7;
        uint4 u = *reinterpret_cast<const uint4*>(&vbufT[((size_t)b * Nn + n0 + row) * 64 + seg * 8]);
        *reinterpret_cast<uint4*>(&vvT[row][seg * 8]) = u;
    }
    __syncthreads();
    int v = t & 63, k0 = t >> 6;
    float acc4[4] = {0.f, 0.f, 0.f, 0.f};
    for (int nl = 0; nl < NCHUNK; nl++) {
        float wv = bf2f(vvT[nl][v]);
#pragma unroll
        for (int j2 = 0; j2 < 4; j2++) acc4[j2] += kks[k0 + 4 * j2][nl] * wv;
    }
#pragma unroll
    for (int j2 = 0; j2 < 4; j2++)
        atomicAdd(&lam[((size_t)b * Kk + k0 + 4 * j2) * Vv + v], acc4[j2]);
}

// ---------------- Kernel 5: fused position-lambda + apply ----------------
// TN=32, 256 threads = (vgp 0..7)x(np 0..31); acc[4 h][8 v]. All staging linear/wide.
#define TN 32
__global__ __launch_bounds__(256, 6) void fused_out_kernel(
    const ushort* __restrict__ qbufT, const ushort* __restrict__ vbufT,
    const ushort* __restrict__ gbuf, const float* __restrict__ lam,
    const float* __restrict__ conv_b, float* __restrict__ out) {
    __shared__ ushort vvsT[54][72];       // [j][v] bf16; n = n0-11+j; rows 144 B
    __shared__ ushort qsT[TN][68];        // [np][k*4+h] bf16; rows 136 B
    __shared__ ushort gsT[Rr][TN][4];     // [r][np][h] bf16 (linear copy of gbuf chunk)
    __shared__ float  lcs[Kk][Vv];        // lam_c + conv_b

    int b = blockIdx.y;
    int n0 = blockIdx.x * TN;
    int t = threadIdx.x;

    // ---- load phase (all globals issued before any LDS write) ----
    // gsT: 368 uint4
    uint4 gld0, gld1;
    {
        int i = t;
        int r = i >> 4, seg = i & 15;
        if (i < 368)
            gld0 = *reinterpret_cast<const uint4*>(&gbuf[(((size_t)b * Rr + r) * Nn + n0) * 4 + seg * 8]);
        int i2 = t + 256;
        int r2 = i2 >> 4, seg2 = i2 & 15;
        if (i2 < 368)
            gld1 = *reinterpret_cast<const uint4*>(&gbuf[(((size_t)b * Rr + r2) * Nn + n0) * 4 + seg2 * 8]);
    }
    // qsT: 512 uint2
    uint2 qld0, qld1;
    {
        int i = t;
        int np = i >> 4, seg = i & 15;
        qld0 = *reinterpret_cast<const uint2*>(&qbufT[((size_t)b * Nn + n0 + np) * 64 + seg * 4]);
        int i2 = t + 256;
        int np2 = i2 >> 4, seg2 = i2 & 15;
        qld1 = *reinterpret_cast<const uint2*>(&qbufT[((size_t)b * Nn + n0 + np2) * 64 + seg2 * 4]);
    }
    // vvsT: 432 uint4 with row zero-fill
    uint4 vld0 = {0, 0, 0, 0}, vld1 = {0, 0, 0, 0};
    {
        int i = t;
        int j = i >> 3, seg = i & 7;
        int nn = n0 - 11 + j;
        if (nn >= 0 && nn < Nn)
            vld0 = *reinterpret_cast<const uint4*>(&vbufT[((size_t)b * Nn + nn) * 64 + seg * 8]);
        int i2 = t + 256;
        int j2 = i2 >> 3, seg2 = i2 & 7;
        int nn2 = n0 - 11 + j2;
        if (i2 < 432 && nn2 >= 0 && nn2 < Nn)
            vld1 = *reinterpret_cast<const uint4*>(&vbufT[((size_t)b * Nn + nn2) * 64 + seg2 * 8]);
    }
    // lcs: 1024 f32
    float lld[4];
#pragma unroll
    for (int m = 0; m < 4; m++) {
        int i = t + 256 * m;
        lld[m] = lam[(size_t)b * Kk * Vv + i] + conv_b[i >> 6];
    }

    // ---- write phase ----
    {
        int i = t;
        if (i < 368) *(reinterpret_cast<uint4*>(gsT) + i) = gld0;
        int i2 = t + 256;
        if (i2 < 368) *(reinterpret_cast<uint4*>(gsT) + i2) = gld1;
    }
    {
        int i = t;
        int np = i >> 4, seg = i & 15;
        *reinterpret_cast<uint2*>(&qsT[np][seg * 4]) = qld0;
        int i2 = t + 256;
        int np2 = i2 >> 4, seg2 = i2 & 15;
        *reinterpret_cast<uint2*>(&qsT[np2][seg2 * 4]) = qld1;
    }
    {
        int i = t;
        int j = i >> 3, seg = i & 7;
        *reinterpret_cast<uint4*>(&vvsT[j][seg * 8]) = vld0;
        int i2 = t + 256;
        if (i2 < 432) {
            int j2 = i2 >> 3, seg2 = i2 & 7;
            *reinterpret_cast<uint4*>(&vvsT[j2][seg2 * 8]) = vld1;
        }
    }
#pragma unroll
    for (int m = 0; m < 4; m++) {
        int i = t + 256 * m;
        lcs[i >> 6][i & 63] = lld[m];
    }
    __syncthreads();

    // ---- main ----
    int np = t & 31;
    int vgp = t >> 5;

    float acc[4][8];
#pragma unroll
    for (int h = 0; h < 4; h++)
#pragma unroll
        for (int vl = 0; vl < 8; vl++) acc[h][vl] = 0.f;

    // position: per r, 1 b64 (g: 4 h) + 1 b128 (vv: 8 v), 32 FMA
#pragma unroll
    for (int r = 0; r < Rr; r++) {
        ushort4 g4 = *reinterpret_cast<const ushort4*>(&gsT[r][np][0]);
        uint4 w4 = *reinterpret_cast<const uint4*>(&vvsT[np + r][vgp * 8]);
        float gh[4] = {bf2f(g4.x), bf2f(g4.y), bf2f(g4.z), bf2f(g4.w)};
        float wv[8];
        wv[0] = bflo(w4.x); wv[1] = bfhi(w4.x);
        wv[2] = bflo(w4.y); wv[3] = bfhi(w4.y);
        wv[4] = bflo(w4.z); wv[5] = bfhi(w4.z);
        wv[6] = bflo(w4.w); wv[7] = bfhi(w4.w);
#pragma unroll
        for (int h = 0; h < 4; h++)
#pragma unroll
            for (int vl = 0; vl < 8; vl++) acc[h][vl] += gh[h] * wv[vl];
    }

    // content: per k, 1 b64 (q: 4 h) + 2 broadcast b128 (lc), 32 FMA
#pragma unroll
    for (int k = 0; k < 16; k++) {
        ushort4 q4 = *reinterpret_cast<const ushort4*>(&qsT[np][k * 4]);
        float qh[4] = {bf2f(q4.x), bf2f(q4.y), bf2f(q4.z), bf2f(q4.w)};
        const float4* lr = reinterpret_cast<const float4*>(&lcs[k][vgp * 8]);
        float4 la = lr[0], lb = lr[1];
        float lv[8] = {la.x, la.y, la.z, la.w, lb.x, lb.y, lb.z, lb.w};
#pragma unroll
        for (int h = 0; h < 4; h++)
#pragma unroll
            for (int vl = 0; vl < 8; vl++) acc[h][vl] += qh[h] * lv[vl];
    }

    // store: coalesced 128 B segments per (h, vl)
    float* ob = out + (size_t)b * 256 * Nn + n0 + np;
#pragma unroll
    for (int h = 0; h < 4; h++)
#pragma unroll
        for (int vl = 0; vl < 8; vl++)
            ob[(size_t)(h * 64 + vgp * 8 + vl) * Nn] = acc[h][vl];
}

extern "C" void kernel_launch(void* const* d_in, const int* in_sizes, int n_in,
                              void* d_out, int out_size, void* d_ws, size_t ws_size,
                              hipStream_t stream) {
    const float* x      = (const float*)d_in[0];
    const float* Wq     = (const float*)d_in[1];
    const float* qg     = (const float*)d_in[2];
    const float* qb     = (const float*)d_in[3];
    const float* qm     = (const float*)d_in[4];
    const float* qv     = (const float*)d_in[5];
    const float* Wk     = (const float*)d_in[6];
    const float* Wv     = (const float*)d_in[7];
    const float* vg     = (const float*)d_in[8];
    const float* vb     = (const float*)d_in[9];
    const float* vm     = (const float*)d_in[10];
    const float* vvar   = (const float*)d_in[11];
    const float* conv_w = (const float*)d_in[12];
    const float* conv_b = (const float*)d_in[13];
    float* out = (float*)d_out;

    float* wsf = (float*)d_ws;
    // layout (float units):
    ushort* Wf16  = (ushort*)wsf;                       // 61440 u16 = 30720 f
    float*  bias  = wsf + 30720;                        // 256 f
    float*  kbuf  = wsf + 30976;                        // 16*16*4096 = 1048576 f
    float*  lam   = wsf + 30976 + 1048576;              // 16384 f
    ushort* qbufT = (ushort*)(wsf + 1095936);           // 16*4096*64 u16 = 2097152 f
    ushort* vbufT = (ushort*)(wsf + 3193088);           // 2097152 f
    ushort* gbuf  = (ushort*)(wsf + 5290240);           // 16*23*4096*4 u16 = 3014656 f

    pack_kernel<<<NCH, 256, 0, stream>>>(Wq, qg, qb, qm, qv, Wk, Wv, vg, vb, vm, vvar,
                                         conv_w, Wf16, bias);
    proj_mfma_kernel<<<dim3(Nn / 64, Bn), 256, 0, stream>>>(x, Wf16, bias,
                                                            qbufT, kbuf, vbufT, gbuf);
    softmax_kernel<<<dim3(Kk, Bn), 256, 0, stream>>>(kbuf);
    hipMemsetAsync(lam, 0, (size_t)Bn * Kk * Vv * sizeof(float), stream);
    lamc_kernel<<<dim3(Nn / NCHUNK, Bn), 256, 0, stream>>>(kbuf, vbufT, lam);
    fused_out_kernel<<<dim3(Nn / TN, Bn), 256, 0, stream>>>(qbufT, vbufT, gbuf, lam,
                                                            conv_b, out);
}

// Round 8
// 88.894 us; speedup vs baseline: 1.0812x; 1.0812x over previous
//
#include <hip/hip_runtime.h>
#include <hip/hip_bf16.h>

typedef unsigned int uint;
typedef unsigned short ushort;

// Dims
#define Bn 16
#define Dd 256
#define Nn 4096
#define Hh 4
#define Kk 16
#define Vv 64
#define Rr 23
#define NCH 240   // 64 q + 16 k + 64 v + 92 g + 4 pad
#define NRT 15    // 240/16 row-tiles

typedef short bf16x8s __attribute__((ext_vector_type(8)));
typedef float f32x4 __attribute__((ext_vector_type(4)));

static __device__ __forceinline__ ushort f2bf(float f) {
    __hip_bfloat16 h = __float2bfloat16(f);
    return __builtin_bit_cast(ushort, h);
}
static __device__ __forceinline__ float bf2f(ushort u) {
    return __uint_as_float(((uint)u) << 16);
}
static __device__ __forceinline__ float bflo(uint u) { return __uint_as_float(u << 16); }
static __device__ __forceinline__ float bfhi(uint u) { return __uint_as_float(u & 0xffff0000u); }

// ---------------- Kernel 1: pack 240 BN-folded rows (bf16, A-fragment order) ----------------
// rows: 0..63 q (BN), 64..79 k, 80..143 v (BN), 144..235 g = conv_w-combined q rows, 236..239 zero
__global__ __launch_bounds__(256) void pack_kernel(
    const float* __restrict__ Wq, const float* __restrict__ qg, const float* __restrict__ qb,
    const float* __restrict__ qm, const float* __restrict__ qv,
    const float* __restrict__ Wk, const float* __restrict__ Wv,
    const float* __restrict__ vg, const float* __restrict__ vb,
    const float* __restrict__ vm, const float* __restrict__ vvar,
    const float* __restrict__ conv_w,
    ushort* __restrict__ Wf16, float* __restrict__ bias) {
    int c = blockIdx.x;       // 0..239
    int d = threadIdx.x;      // 0..255
    float wval = 0.f, bs = 0.f;
    if (c < 64) {
        float scale = qg[c] * rsqrtf(qv[c] + 1e-5f);
        bs = qb[c] - qm[c] * scale;
        wval = Wq[c * Dd + d] * scale;
    } else if (c < 80) {
        wval = Wk[(c - 64) * Dd + d];
    } else if (c < 144) {
        int j = c - 80;
        float scale = vg[j] * rsqrtf(vvar[j] + 1e-5f);
        bs = vb[j] - vm[j] * scale;
        wval = Wv[j * Dd + d] * scale;
    } else if (c < 236) {
        int cg = c - 144;
        int h = cg / 23, r = cg - h * 23;
        float wsum = 0.f, bsum = 0.f;
        for (int k = 0; k < 16; k++) {
            int qc = h * 16 + k;
            float scale = qg[qc] * rsqrtf(qv[qc] + 1e-5f);
            float cw = conv_w[k * Rr + r];
            wsum += cw * (Wq[qc * Dd + d] * scale);
            bsum += cw * (qb[qc] - qm[qc] * scale);
        }
        wval = wsum; bs = bsum;
    }
    int rt = c >> 4, lm = c & 15;
    int kk = d >> 5, hi = (d >> 3) & 3, j = d & 7;
    Wf16[((rt * 8 + kk) * 64 + hi * 16 + lm) * 8 + j] = f2bf(wval);
    if (d == 0) bias[c] = bs;
}

// ---------------- Kernel 2: MFMA projection -> 4 consumer-layout buffers ----------------
// Epilogue: transpose via LDS (reusing Wlds), then fully-coalesced uint4 global stores.
__global__ __launch_bounds__(256, 4) void proj_mfma_kernel(
    const float* __restrict__ x, const ushort* __restrict__ Wf16,
    const float* __restrict__ bias,
    ushort* __restrict__ qbufT, float* __restrict__ kbuf,
    ushort* __restrict__ vbufT, ushort* __restrict__ gbuf) {
    __shared__ ushort Wlds[NRT * 2 * 64 * 8];   // 15360 ushorts = 30720 B

    int b = blockIdx.y;
    int n0 = blockIdx.x * 64;
    int t = threadIdx.x;
    int w = t >> 6, l = t & 63;
    int lm = l & 15, hi = l >> 4;
    int n = n0 + w * 16 + lm;     // this lane's output column

    const uint* WfU = (const uint*)Wf16;
    uint* WldsU = (uint*)Wlds;

    f32x4 acc[NRT];
#pragma unroll
    for (int rt = 0; rt < NRT; rt++) acc[rt] = (f32x4){0.f, 0.f, 0.f, 0.f};

    const float* xb = x + (size_t)b * Dd * Nn + n;

    for (int p = 0; p < 4; p++) {
        int kb = p * 2;
        if (p) __syncthreads();
#pragma unroll
        for (int i = 0; i < 30; i++) {
            int flat = t + 256 * i;
            int f2 = flat >> 8;          // rt*2 + kkl
            int rt = f2 >> 1, kkl = f2 & 1;
            WldsU[flat] = WfU[((rt * 8 + kb + kkl) << 8) + (flat & 255)];
        }
        __syncthreads();
#pragma unroll
        for (int kkl = 0; kkl < 2; kkl++) {
            int kk = kb + kkl;
            const float* xp = xb + (size_t)(kk * 32 + hi * 8) * Nn;
            float f[8];
#pragma unroll
            for (int j = 0; j < 8; j++) f[j] = xp[(size_t)j * Nn];
            bf16x8s bfrag;
#pragma unroll
            for (int j = 0; j < 8; j++) bfrag[j] = (short)f2bf(f[j]);
#pragma unroll
            for (int rt = 0; rt < NRT; rt++) {
                bf16x8s afrag = *reinterpret_cast<const bf16x8s*>(
                    &Wlds[(size_t)((rt * 2 + kkl) * 64 + l) * 8]);
                acc[rt] = __builtin_amdgcn_mfma_f32_16x16x32_bf16(afrag, bfrag, acc[rt], 0, 0, 0);
            }
        }
    }

    // ---- epilogue ----
    // kbuf (rows 64..79): channel-major, already coalesced -> direct store
#pragma unroll
    for (int rr = 0; rr < 4; rr++) {
        int kc = hi * 4 + rr;
        kbuf[((size_t)b * 16 + kc) * Nn + n] = acc[4][rr] + bias[64 + kc];
    }

    __syncthreads();   // done reading Wlds; reuse as transpose buffer
    // LDS layout (ushort offsets): q = nl*72+pos (64 rows x 72), v = 4608 + nl*72+v,
    // g = 9216 + r*264 + nl*4 + h  (23 x 264)
    {
        int nl = w * 16 + lm;
        // q rows 0..63: pos = k*4+h, k = hi*4+rr, h = rt
#pragma unroll
        for (int rt = 0; rt < 4; rt++)
#pragma unroll
            for (int rr = 0; rr < 4; rr++) {
                int kq = hi * 4 + rr;
                Wlds[nl * 72 + kq * 4 + rt] = f2bf(acc[rt][rr] + bias[rt * 16 + kq]);
            }
        // v rows 80..143
#pragma unroll
        for (int rt = 5; rt < 9; rt++)
#pragma unroll
            for (int rr = 0; rr < 4; rr++) {
                int v = (rt - 5) * 16 + hi * 4 + rr;
                Wlds[4608 + nl * 72 + v] = f2bf(acc[rt][rr] + bias[80 + v]);
            }
        // g rows 144..235: cg = h*23+r
#pragma unroll
        for (int rt = 9; rt < 15; rt++)
#pragma unroll
            for (int rr = 0; rr < 4; rr++) {
                int cg = rt * 16 + hi * 4 + rr - 144;
                if (cg < 92) {
                    int h = (cg * 713) >> 14;      // floor(cg/23), exact for 0..91
                    int r = cg - h * 23;
                    Wlds[9216 + r * 264 + nl * 4 + h] = f2bf(acc[rt][rr] + bias[144 + cg]);
                }
            }
    }
    __syncthreads();

    // ---- coalesced stores from LDS ----
    // qbufT: 64 rows x 8 uint4
#pragma unroll
    for (int m = 0; m < 2; m++) {
        int i = t + 256 * m;
        int row = i >> 3, seg = i & 7;
        uint4 u = *reinterpret_cast<const uint4*>(&Wlds[row * 72 + seg * 8]);
        *reinterpret_cast<uint4*>(&qbufT[((size_t)b * Nn + n0 + row) * 64 + seg * 8]) = u;
    }
    // vbufT: 64 rows x 8 uint4
#pragma unroll
    for (int m = 0; m < 2; m++) {
        int i = t + 256 * m;
        int row = i >> 3, seg = i & 7;
        uint4 u = *reinterpret_cast<const uint4*>(&Wlds[4608 + row * 72 + seg * 8]);
        *reinterpret_cast<uint4*>(&vbufT[((size_t)b * Nn + n0 + row) * 64 + seg * 8]) = u;
    }
    // gbuf: 23 r x 32 uint4 = 736
#pragma unroll
    for (int m = 0; m < 3; m++) {
        int i = t + 256 * m;
        if (i < 736) {
            int r = i >> 5, seg = i & 31;
            uint4 u = *reinterpret_cast<const uint4*>(&Wlds[9216 + r * 264 + seg * 8]);
            *reinterpret_cast<uint4*>(&gbuf[(((size_t)b * Rr + r) * Nn + n0) * 4 + seg * 8]) = u;
        }
    }
}

// ---------------- Kernel 3: softmax over n for k channels (kbuf) ----------------
__global__ __launch_bounds__(256) void softmax_kernel(float* __restrict__ kbuf) {
    int b = blockIdx.y, kc = blockIdx.x;
    float* row = kbuf + ((size_t)b * 16 + kc) * Nn;
    int t = threadIdx.x;
    float vals[16];
    float m = -1e30f;
#pragma unroll
    for (int i = 0; i < 16; i++) {
        vals[i] = row[t + 256 * i];
        m = fmaxf(m, vals[i]);
    }
#pragma unroll
    for (int off = 32; off; off >>= 1) m = fmaxf(m, __shfl_xor(m, off));
    __shared__ float sm[4], ss[4];
    int wave = t >> 6;
    if ((t & 63) == 0) sm[wave] = m;
    __syncthreads();
    m = fmaxf(fmaxf(sm[0], sm[1]), fmaxf(sm[2], sm[3]));
    float s = 0.f;
#pragma unroll
    for (int i = 0; i < 16; i++) {
        vals[i] = __expf(vals[i] - m);
        s += vals[i];
    }
#pragma unroll
    for (int off = 32; off; off >>= 1) s += __shfl_xor(s, off);
    if ((t & 63) == 0) ss[wave] = s;
    __syncthreads();
    s = ss[0] + ss[1] + ss[2] + ss[3];
    float inv = 1.f / s;
#pragma unroll
    for (int i = 0; i < 16; i++) row[t + 256 * i] = vals[i] * inv;
}

// ---------------- Kernel 4: lam_c[b][16][64] = sum_n kk*vv ----------------
#define NCHUNK 128
__global__ __launch_bounds__(256) void lamc_kernel(
    const float* __restrict__ kbuf, const ushort* __restrict__ vbufT,
    float* __restrict__ lam) {
    int b = blockIdx.y;
    int n0 = blockIdx.x * NCHUNK;
    __shared__ float kks[Kk][NCHUNK + 1];   // 8256 B
    __shared__ ushort vvT[NCHUNK][72];      // 18432 B, rows 144 B
    int t = threadIdx.x;
#pragma unroll
    for (int m = 0; m < 2; m++) {
        int i = t + 256 * m;
        int r = i >> 5, seg = i & 31;
        float4 f = *reinterpret_cast<const float4*>(&kbuf[((size_t)b * 16 + r) * Nn + n0 + seg * 4]);
        kks[r][seg * 4 + 0] = f.x;
        kks[r][seg * 4 + 1] = f.y;
        kks[r][seg * 4 + 2] = f.z;
        kks[r][seg * 4 + 3] = f.w;
    }
#pragma unroll
    for (int m = 0; m < 4; m++) {
        int i = t + 256 * m;
        int row = i >> 3, seg = i & 7;
        uint4 u = *reinterpret_cast<const uint4*>(&vbufT[((size_t)b * Nn + n0 + row) * 64 + seg * 8]);
        *reinterpret_cast<uint4*>(&vvT[row][seg * 8]) = u;
    }
    __syncthreads();
    int v = t & 63, k0 = t >> 6;
    float acc4[4] = {0.f, 0.f, 0.f, 0.f};
    for (int nl = 0; nl < NCHUNK; nl++) {
        float wv = bf2f(vvT[nl][v]);
#pragma unroll
        for (int j2 = 0; j2 < 4; j2++) acc4[j2] += kks[k0 + 4 * j2][nl] * wv;
    }
#pragma unroll
    for (int j2 = 0; j2 < 4; j2++)
        atomicAdd(&lam[((size_t)b * Kk + k0 + 4 * j2) * Vv + v], acc4[j2]);
}

// ---------------- Kernel 5: fused position-lambda + apply ----------------
// TN=32, 256 threads = (vgp 0..7)x(np 0..31); acc[4 h][8 v]. All staging linear/wide.
#define TN 32
__global__ __launch_bounds__(256, 6) void fused_out_kernel(
    const ushort* __restrict__ qbufT, const ushort* __restrict__ vbufT,
    const ushort* __restrict__ gbuf, const float* __restrict__ lam,
    const float* __restrict__ conv_b, float* __restrict__ out) {
    __shared__ ushort vvsT[54][72];       // [j][v] bf16; n = n0-11+j; rows 144 B
    __shared__ ushort qsT[TN][68];        // [np][k*4+h] bf16; rows 136 B
    __shared__ ushort gsT[Rr][TN][4];     // [r][np][h] bf16 (linear copy of gbuf chunk)
    __shared__ float  lcs[Kk][Vv];        // lam_c + conv_b

    int b = blockIdx.y;
    int n0 = blockIdx.x * TN;
    int t = threadIdx.x;

    // ---- load phase (all globals issued before any LDS write) ----
    uint4 gld0, gld1;
    {
        int i = t;
        int r = i >> 4, seg = i & 15;
        if (i < 368)
            gld0 = *reinterpret_cast<const uint4*>(&gbuf[(((size_t)b * Rr + r) * Nn + n0) * 4 + seg * 8]);
        int i2 = t + 256;
        int r2 = i2 >> 4, seg2 = i2 & 15;
        if (i2 < 368)
            gld1 = *reinterpret_cast<const uint4*>(&gbuf[(((size_t)b * Rr + r2) * Nn + n0) * 4 + seg2 * 8]);
    }
    uint2 qld0, qld1;
    {
        int i = t;
        int np = i >> 4, seg = i & 15;
        qld0 = *reinterpret_cast<const uint2*>(&qbufT[((size_t)b * Nn + n0 + np) * 64 + seg * 4]);
        int i2 = t + 256;
        int np2 = i2 >> 4, seg2 = i2 & 15;
        qld1 = *reinterpret_cast<const uint2*>(&qbufT[((size_t)b * Nn + n0 + np2) * 64 + seg2 * 4]);
    }
    uint4 vld0 = {0, 0, 0, 0}, vld1 = {0, 0, 0, 0};
    {
        int i = t;
        int j = i >> 3, seg = i & 7;
        int nn = n0 - 11 + j;
        if (nn >= 0 && nn < Nn)
            vld0 = *reinterpret_cast<const uint4*>(&vbufT[((size_t)b * Nn + nn) * 64 + seg * 8]);
        int i2 = t + 256;
        int j2 = i2 >> 3, seg2 = i2 & 7;
        int nn2 = n0 - 11 + j2;
        if (i2 < 432 && nn2 >= 0 && nn2 < Nn)
            vld1 = *reinterpret_cast<const uint4*>(&vbufT[((size_t)b * Nn + nn2) * 64 + seg2 * 8]);
    }
    float lld[4];
#pragma unroll
    for (int m = 0; m < 4; m++) {
        int i = t + 256 * m;
        lld[m] = lam[(size_t)b * Kk * Vv + i] + conv_b[i >> 6];
    }

    // ---- write phase ----
    {
        int i = t;
        if (i < 368) *(reinterpret_cast<uint4*>(gsT) + i) = gld0;
        int i2 = t + 256;
        if (i2 < 368) *(reinterpret_cast<uint4*>(gsT) + i2) = gld1;
    }
    {
        int i = t;
        int np = i >> 4, seg = i & 15;
        *reinterpret_cast<uint2*>(&qsT[np][seg * 4]) = qld0;
        int i2 = t + 256;
        int np2 = i2 >> 4, seg2 = i2 & 15;
        *reinterpret_cast<uint2*>(&qsT[np2][seg2 * 4]) = qld1;
    }
    {
        int i = t;
        int j = i >> 3, seg = i & 7;
        *reinterpret_cast<uint4*>(&vvsT[j][seg * 8]) = vld0;
        int i2 = t + 256;
        if (i2 < 432) {
            int j2 = i2 >> 3, seg2 = i2 & 7;
            *reinterpret_cast<uint4*>(&vvsT[j2][seg2 * 8]) = vld1;
        }
    }
#pragma unroll
    for (int m = 0; m < 4; m++) {
        int i = t + 256 * m;
        lcs[i >> 6][i & 63] = lld[m];
    }
    __syncthreads();

    // ---- main ----
    int np = t & 31;
    int vgp = t >> 5;

    float acc[4][8];
#pragma unroll
    for (int h = 0; h < 4; h++)
#pragma unroll
        for (int vl = 0; vl < 8; vl++) acc[h][vl] = 0.f;

#pragma unroll
    for (int r = 0; r < Rr; r++) {
        ushort4 g4 = *reinterpret_cast<const ushort4*>(&gsT[r][np][0]);
        uint4 w4 = *reinterpret_cast<const uint4*>(&vvsT[np + r][vgp * 8]);
        float gh[4] = {bf2f(g4.x), bf2f(g4.y), bf2f(g4.z), bf2f(g4.w)};
        float wv[8];
        wv[0] = bflo(w4.x); wv[1] = bfhi(w4.x);
        wv[2] = bflo(w4.y); wv[3] = bfhi(w4.y);
        wv[4] = bflo(w4.z); wv[5] = bfhi(w4.z);
        wv[6] = bflo(w4.w); wv[7] = bfhi(w4.w);
#pragma unroll
        for (int h = 0; h < 4; h++)
#pragma unroll
            for (int vl = 0; vl < 8; vl++) acc[h][vl] += gh[h] * wv[vl];
    }

#pragma unroll
    for (int k = 0; k < 16; k++) {
        ushort4 q4 = *reinterpret_cast<const ushort4*>(&qsT[np][k * 4]);
        float qh[4] = {bf2f(q4.x), bf2f(q4.y), bf2f(q4.z), bf2f(q4.w)};
        const float4* lr = reinterpret_cast<const float4*>(&lcs[k][vgp * 8]);
        float4 la = lr[0], lb = lr[1];
        float lv[8] = {la.x, la.y, la.z, la.w, lb.x, lb.y, lb.z, lb.w};
#pragma unroll
        for (int h = 0; h < 4; h++)
#pragma unroll
            for (int vl = 0; vl < 8; vl++) acc[h][vl] += qh[h] * lv[vl];
    }

    float* ob = out + (size_t)b * 256 * Nn + n0 + np;
#pragma unroll
    for (int h = 0; h < 4; h++)
#pragma unroll
        for (int vl = 0; vl < 8; vl++)
            ob[(size_t)(h * 64 + vgp * 8 + vl) * Nn] = acc[h][vl];
}

extern "C" void kernel_launch(void* const* d_in, const int* in_sizes, int n_in,
                              void* d_out, int out_size, void* d_ws, size_t ws_size,
                              hipStream_t stream) {
    const float* x      = (const float*)d_in[0];
    const float* Wq     = (const float*)d_in[1];
    const float* qg     = (const float*)d_in[2];
    const float* qb     = (const float*)d_in[3];
    const float* qm     = (const float*)d_in[4];
    const float* qv     = (const float*)d_in[5];
    const float* Wk     = (const float*)d_in[6];
    const float* Wv     = (const float*)d_in[7];
    const float* vg     = (const float*)d_in[8];
    const float* vb     = (const float*)d_in[9];
    const float* vm     = (const float*)d_in[10];
    const float* vvar   = (const float*)d_in[11];
    const float* conv_w = (const float*)d_in[12];
    const float* conv_b = (const float*)d_in[13];
    float* out = (float*)d_out;

    float* wsf = (float*)d_ws;
    ushort* Wf16  = (ushort*)wsf;                       // 61440 u16 = 30720 f
    float*  bias  = wsf + 30720;                        // 256 f
    float*  kbuf  = wsf + 30976;                        // 16*16*4096 = 1048576 f
    float*  lam   = wsf + 30976 + 1048576;              // 16384 f
    ushort* qbufT = (ushort*)(wsf + 1095936);           // 16*4096*64 u16
    ushort* vbufT = (ushort*)(wsf + 3193088);           // 16*4096*64 u16
    ushort* gbuf  = (ushort*)(wsf + 5290240);           // 16*23*4096*4 u16

    pack_kernel<<<NCH, 256, 0, stream>>>(Wq, qg, qb, qm, qv, Wk, Wv, vg, vb, vm, vvar,
                                         conv_w, Wf16, bias);
    proj_mfma_kernel<<<dim3(Nn / 64, Bn), 256, 0, stream>>>(x, Wf16, bias,
                                                            qbufT, kbuf, vbufT, gbuf);
    softmax_kernel<<<dim3(Kk, Bn), 256, 0, stream>>>(kbuf);
    hipMemsetAsync(lam, 0, (size_t)Bn * Kk * Vv * sizeof(float), stream);
    lamc_kernel<<<dim3(Nn / NCHUNK, Bn), 256, 0, stream>>>(kbuf, vbufT, lam);
    fused_out_kernel<<<dim3(Nn / TN, Bn), 256, 0, stream>>>(qbufT, vbufT, gbuf, lam,
                                                            conv_b, out);
}

// Round 9
// 79.410 us; speedup vs baseline: 1.2103x; 1.1194x over previous
//
#include <hip/hip_runtime.h>
#include <hip/hip_bf16.h>

typedef unsigned int uint;
typedef unsigned short ushort;

// Dims
#define Bn 16
#define Dd 256
#define Nn 4096
#define Hh 4
#define Kk 16
#define Vv 64
#define Rr 23
#define NCH 240   // 64 q + 16 k + 64 v + 92 g + 4 pad
#define NRT 15    // 240/16 row-tiles

typedef short bf16x8s __attribute__((ext_vector_type(8)));
typedef float f32x4 __attribute__((ext_vector_type(4)));

static __device__ __forceinline__ ushort f2bf(float f) {
    __hip_bfloat16 h = __float2bfloat16(f);
    return __builtin_bit_cast(ushort, h);
}
static __device__ __forceinline__ float bf2f(ushort u) {
    return __uint_as_float(((uint)u) << 16);
}
static __device__ __forceinline__ float bflo(uint u) { return __uint_as_float(u << 16); }
static __device__ __forceinline__ float bfhi(uint u) { return __uint_as_float(u & 0xffff0000u); }

// ---------------- Kernel 1: pack 240 BN-folded rows (bf16, A-fragment order) ----------------
// rows: 0..63 q (BN), 64..79 k, 80..143 v (BN), 144..235 g = conv_w-combined q rows, 236..239 zero
__global__ __launch_bounds__(256) void pack_kernel(
    const float* __restrict__ Wq, const float* __restrict__ qg, const float* __restrict__ qb,
    const float* __restrict__ qm, const float* __restrict__ qv,
    const float* __restrict__ Wk, const float* __restrict__ Wv,
    const float* __restrict__ vg, const float* __restrict__ vb,
    const float* __restrict__ vm, const float* __restrict__ vvar,
    const float* __restrict__ conv_w,
    ushort* __restrict__ Wf16, float* __restrict__ bias) {
    int c = blockIdx.x;       // 0..239
    int d = threadIdx.x;      // 0..255
    float wval = 0.f, bs = 0.f;
    if (c < 64) {
        float scale = qg[c] * rsqrtf(qv[c] + 1e-5f);
        bs = qb[c] - qm[c] * scale;
        wval = Wq[c * Dd + d] * scale;
    } else if (c < 80) {
        wval = Wk[(c - 64) * Dd + d];
    } else if (c < 144) {
        int j = c - 80;
        float scale = vg[j] * rsqrtf(vvar[j] + 1e-5f);
        bs = vb[j] - vm[j] * scale;
        wval = Wv[j * Dd + d] * scale;
    } else if (c < 236) {
        int cg = c - 144;
        int h = cg / 23, r = cg - h * 23;
        float wsum = 0.f, bsum = 0.f;
        for (int k = 0; k < 16; k++) {
            int qc = h * 16 + k;
            float scale = qg[qc] * rsqrtf(qv[qc] + 1e-5f);
            float cw = conv_w[k * Rr + r];
            wsum += cw * (Wq[qc * Dd + d] * scale);
            bsum += cw * (qb[qc] - qm[qc] * scale);
        }
        wval = wsum; bs = bsum;
    }
    int rt = c >> 4, lm = c & 15;
    int kk = d >> 5, hi = (d >> 3) & 3, j = d & 7;
    Wf16[((rt * 8 + kk) * 64 + hi * 16 + lm) * 8 + j] = f2bf(wval);
    if (d == 0) bias[c] = bs;
}

// ---------------- Kernel 2: MFMA projection -> 4 consumer-layout buffers ----------------
// x staged ONCE into LDS in B-fragment order (batched float4 loads + in-LDS transpose);
// k-loop has zero global loads. Epilogue transposes via Wlds then coalesced uint4 stores.
__global__ __launch_bounds__(256, 2) void proj_mfma_kernel(
    const float* __restrict__ x, const ushort* __restrict__ Wf16,
    const float* __restrict__ bias,
    ushort* __restrict__ qbufT, float* __restrict__ kbuf,
    ushort* __restrict__ vbufT, ushort* __restrict__ gbuf) {
    __shared__ ushort Xlds[8 * 4 * 64 * 8];     // [kk][hi][n][j] bf16 = 32768 B
    __shared__ ushort Wlds[NRT * 2 * 64 * 8];   // 30720 B (2 k-steps per phase)

    int b = blockIdx.y;
    int n0 = blockIdx.x * 64;
    int t = threadIdx.x;
    int w = t >> 6, l = t & 63;
    int lm = l & 15, hi = l >> 4;
    int n = n0 + w * 16 + lm;     // this lane's output column

    const uint* WfU = (const uint*)Wf16;
    uint* WldsU = (uint*)Wlds;

    f32x4 acc[NRT];
#pragma unroll
    for (int rt = 0; rt < NRT; rt++) acc[rt] = (f32x4){0.f, 0.f, 0.f, 0.f};

    // ---- stage x: 16 batched float4 loads, then transpose-write to LDS ----
    {
        const float* xb0 = x + (size_t)b * Dd * Nn + n0;
        int drow = t >> 4;            // 0..15 within pass
        int n4 = (t & 15) * 4;        // 4 consecutive n
        float4 xr[16];
#pragma unroll
        for (int p = 0; p < 16; p++) {
            int d = p * 16 + drow;
            xr[p] = *reinterpret_cast<const float4*>(&xb0[(size_t)d * Nn + n4]);
        }
#pragma unroll
        for (int p = 0; p < 16; p++) {
            int d = p * 16 + drow;
            int kk = d >> 5, dh = (d >> 3) & 3, jd = d & 7;
            ushort* xp = &Xlds[((kk * 4 + dh) * 64 + n4) * 8 + jd];
            xp[0]  = f2bf(xr[p].x);
            xp[8]  = f2bf(xr[p].y);
            xp[16] = f2bf(xr[p].z);
            xp[24] = f2bf(xr[p].w);
        }
    }
    __syncthreads();

    // ---- K loop: 4 phases x 2 ksteps; only W-stage touches global ----
    for (int p = 0; p < 4; p++) {
        int kb = p * 2;
        if (p) __syncthreads();
#pragma unroll
        for (int i = 0; i < 30; i++) {
            int flat = t + 256 * i;
            int f2 = flat >> 8;          // rt*2 + kkl
            int rt = f2 >> 1, kkl = f2 & 1;
            WldsU[flat] = WfU[((rt * 8 + kb + kkl) << 8) + (flat & 255)];
        }
        __syncthreads();
#pragma unroll
        for (int kkl = 0; kkl < 2; kkl++) {
            int kk = kb + kkl;
            bf16x8s bfrag = *reinterpret_cast<const bf16x8s*>(
                &Xlds[((kk * 4 + hi) * 64 + w * 16 + lm) * 8]);
#pragma unroll
            for (int rt = 0; rt < NRT; rt++) {
                bf16x8s afrag = *reinterpret_cast<const bf16x8s*>(
                    &Wlds[(size_t)((rt * 2 + kkl) * 64 + l) * 8]);
                acc[rt] = __builtin_amdgcn_mfma_f32_16x16x32_bf16(afrag, bfrag, acc[rt], 0, 0, 0);
            }
        }
    }

    // ---- epilogue ----
    // kbuf (rows 64..79): channel-major, already coalesced -> direct store
#pragma unroll
    for (int rr = 0; rr < 4; rr++) {
        int kc = hi * 4 + rr;
        kbuf[((size_t)b * 16 + kc) * Nn + n] = acc[4][rr] + bias[64 + kc];
    }

    __syncthreads();   // done reading Wlds; reuse as transpose buffer
    // LDS layout (ushort offsets): q = nl*72+pos (64 rows x 72), v = 4608 + nl*72+v,
    // g = 9216 + r*264 + nl*4 + h  (23 x 264)
    {
        int nl = w * 16 + lm;
        // q rows 0..63: pos = k*4+h, k = hi*4+rr, h = rt
#pragma unroll
        for (int rt = 0; rt < 4; rt++)
#pragma unroll
            for (int rr = 0; rr < 4; rr++) {
                int kq = hi * 4 + rr;
                Wlds[nl * 72 + kq * 4 + rt] = f2bf(acc[rt][rr] + bias[rt * 16 + kq]);
            }
        // v rows 80..143
#pragma unroll
        for (int rt = 5; rt < 9; rt++)
#pragma unroll
            for (int rr = 0; rr < 4; rr++) {
                int v = (rt - 5) * 16 + hi * 4 + rr;
                Wlds[4608 + nl * 72 + v] = f2bf(acc[rt][rr] + bias[80 + v]);
            }
        // g rows 144..235: cg = h*23+r
#pragma unroll
        for (int rt = 9; rt < 15; rt++)
#pragma unroll
            for (int rr = 0; rr < 4; rr++) {
                int cg = rt * 16 + hi * 4 + rr - 144;
                if (cg < 92) {
                    int h = (cg * 713) >> 14;      // floor(cg/23), exact for 0..91
                    int r = cg - h * 23;
                    Wlds[9216 + r * 264 + nl * 4 + h] = f2bf(acc[rt][rr] + bias[144 + cg]);
                }
            }
    }
    __syncthreads();

    // ---- coalesced stores from LDS ----
#pragma unroll
    for (int m = 0; m < 2; m++) {
        int i = t + 256 * m;
        int row = i >> 3, seg = i & 7;
        uint4 u = *reinterpret_cast<const uint4*>(&Wlds[row * 72 + seg * 8]);
        *reinterpret_cast<uint4*>(&qbufT[((size_t)b * Nn + n0 + row) * 64 + seg * 8]) = u;
    }
#pragma unroll
    for (int m = 0; m < 2; m++) {
        int i = t + 256 * m;
        int row = i >> 3, seg = i & 7;
        uint4 u = *reinterpret_cast<const uint4*>(&Wlds[4608 + row * 72 + seg * 8]);
        *reinterpret_cast<uint4*>(&vbufT[((size_t)b * Nn + n0 + row) * 64 + seg * 8]) = u;
    }
#pragma unroll
    for (int m = 0; m < 3; m++) {
        int i = t + 256 * m;
        if (i < 736) {
            int r = i >> 5, seg = i & 31;
            uint4 u = *reinterpret_cast<const uint4*>(&Wlds[9216 + r * 264 + seg * 8]);
            *reinterpret_cast<uint4*>(&gbuf[(((size_t)b * Rr + r) * Nn + n0) * 4 + seg * 8]) = u;
        }
    }
}

// ---------------- Kernel 3: softmax over n for k channels (kbuf) ----------------
__global__ __launch_bounds__(256) void softmax_kernel(float* __restrict__ kbuf) {
    int b = blockIdx.y, kc = blockIdx.x;
    float* row = kbuf + ((size_t)b * 16 + kc) * Nn;
    int t = threadIdx.x;
    float vals[16];
    float m = -1e30f;
#pragma unroll
    for (int i = 0; i < 16; i++) {
        vals[i] = row[t + 256 * i];
        m = fmaxf(m, vals[i]);
    }
#pragma unroll
    for (int off = 32; off; off >>= 1) m = fmaxf(m, __shfl_xor(m, off));
    __shared__ float sm[4], ss[4];
    int wave = t >> 6;
    if ((t & 63) == 0) sm[wave] = m;
    __syncthreads();
    m = fmaxf(fmaxf(sm[0], sm[1]), fmaxf(sm[2], sm[3]));
    float s = 0.f;
#pragma unroll
    for (int i = 0; i < 16; i++) {
        vals[i] = __expf(vals[i] - m);
        s += vals[i];
    }
#pragma unroll
    for (int off = 32; off; off >>= 1) s += __shfl_xor(s, off);
    if ((t & 63) == 0) ss[wave] = s;
    __syncthreads();
    s = ss[0] + ss[1] + ss[2] + ss[3];
    float inv = 1.f / s;
#pragma unroll
    for (int i = 0; i < 16; i++) row[t + 256 * i] = vals[i] * inv;
}

// ---------------- Kernel 4: lam_c[b][16][64] = sum_n kk*vv ----------------
#define NCHUNK 128
__global__ __launch_bounds__(256) void lamc_kernel(
    const float* __restrict__ kbuf, const ushort* __restrict__ vbufT,
    float* __restrict__ lam) {
    int b = blockIdx.y;
    int n0 = blockIdx.x * NCHUNK;
    __shared__ float kks[Kk][NCHUNK + 1];   // 8256 B
    __shared__ ushort vvT[NCHUNK][72];      // 18432 B, rows 144 B
    int t = threadIdx.x;
#pragma unroll
    for (int m = 0; m < 2; m++) {
        int i = t + 256 * m;
        int r = i >> 5, seg = i & 31;
        float4 f = *reinterpret_cast<const float4*>(&kbuf[((size_t)b * 16 + r) * Nn + n0 + seg * 4]);
        kks[r][seg * 4 + 0] = f.x;
        kks[r][seg * 4 + 1] = f.y;
        kks[r][seg * 4 + 2] = f.z;
        kks[r][seg * 4 + 3] = f.w;
    }
#pragma unroll
    for (int m = 0; m < 4; m++) {
        int i = t + 256 * m;
        int row = i >> 3, seg = i & 7;
        uint4 u = *reinterpret_cast<const uint4*>(&vbufT[((size_t)b * Nn + n0 + row) * 64 + seg * 8]);
        *reinterpret_cast<uint4*>(&vvT[row][seg * 8]) = u;
    }
    __syncthreads();
    int v = t & 63, k0 = t >> 6;
    float acc4[4] = {0.f, 0.f, 0.f, 0.f};
    for (int nl = 0; nl < NCHUNK; nl++) {
        float wv = bf2f(vvT[nl][v]);
#pragma unroll
        for (int j2 = 0; j2 < 4; j2++) acc4[j2] += kks[k0 + 4 * j2][nl] * wv;
    }
#pragma unroll
    for (int j2 = 0; j2 < 4; j2++)
        atomicAdd(&lam[((size_t)b * Kk + k0 + 4 * j2) * Vv + v], acc4[j2]);
}

// ---------------- Kernel 5: fused position-lambda + apply ----------------
// TN=32, 256 threads = (vgp 0..7)x(np 0..31); acc[4 h][8 v]. All staging linear/wide.
#define TN 32
__global__ __launch_bounds__(256, 6) void fused_out_kernel(
    const ushort* __restrict__ qbufT, const ushort* __restrict__ vbufT,
    const ushort* __restrict__ gbuf, const float* __restrict__ lam,
    const float* __restrict__ conv_b, float* __restrict__ out) {
    __shared__ ushort vvsT[54][72];       // [j][v] bf16; n = n0-11+j; rows 144 B
    __shared__ ushort qsT[TN][68];        // [np][k*4+h] bf16; rows 136 B
    __shared__ ushort gsT[Rr][TN][4];     // [r][np][h] bf16 (linear copy of gbuf chunk)
    __shared__ float  lcs[Kk][Vv];        // lam_c + conv_b

    int b = blockIdx.y;
    int n0 = blockIdx.x * TN;
    int t = threadIdx.x;

    // ---- load phase (all globals issued before any LDS write) ----
    uint4 gld0, gld1;
    {
        int i = t;
        int r = i >> 4, seg = i & 15;
        if (i < 368)
            gld0 = *reinterpret_cast<const uint4*>(&gbuf[(((size_t)b * Rr + r) * Nn + n0) * 4 + seg * 8]);
        int i2 = t + 256;
        int r2 = i2 >> 4, seg2 = i2 & 15;
        if (i2 < 368)
            gld1 = *reinterpret_cast<const uint4*>(&gbuf[(((size_t)b * Rr + r2) * Nn + n0) * 4 + seg2 * 8]);
    }
    uint2 qld0, qld1;
    {
        int i = t;
        int np = i >> 4, seg = i & 15;
        qld0 = *reinterpret_cast<const uint2*>(&qbufT[((size_t)b * Nn + n0 + np) * 64 + seg * 4]);
        int i2 = t + 256;
        int np2 = i2 >> 4, seg2 = i2 & 15;
        qld1 = *reinterpret_cast<const uint2*>(&qbufT[((size_t)b * Nn + n0 + np2) * 64 + seg2 * 4]);
    }
    uint4 vld0 = {0, 0, 0, 0}, vld1 = {0, 0, 0, 0};
    {
        int i = t;
        int j = i >> 3, seg = i & 7;
        int nn = n0 - 11 + j;
        if (nn >= 0 && nn < Nn)
            vld0 = *reinterpret_cast<const uint4*>(&vbufT[((size_t)b * Nn + nn) * 64 + seg * 8]);
        int i2 = t + 256;
        int j2 = i2 >> 3, seg2 = i2 & 7;
        int nn2 = n0 - 11 + j2;
        if (i2 < 432 && nn2 >= 0 && nn2 < Nn)
            vld1 = *reinterpret_cast<const uint4*>(&vbufT[((size_t)b * Nn + nn2) * 64 + seg2 * 8]);
    }
    float lld[4];
#pragma unroll
    for (int m = 0; m < 4; m++) {
        int i = t + 256 * m;
        lld[m] = lam[(size_t)b * Kk * Vv + i] + conv_b[i >> 6];
    }

    // ---- write phase ----
    {
        int i = t;
        if (i < 368) *(reinterpret_cast<uint4*>(gsT) + i) = gld0;
        int i2 = t + 256;
        if (i2 < 368) *(reinterpret_cast<uint4*>(gsT) + i2) = gld1;
    }
    {
        int i = t;
        int np = i >> 4, seg = i & 15;
        *reinterpret_cast<uint2*>(&qsT[np][seg * 4]) = qld0;
        int i2 = t + 256;
        int np2 = i2 >> 4, seg2 = i2 & 15;
        *reinterpret_cast<uint2*>(&qsT[np2][seg2 * 4]) = qld1;
    }
    {
        int i = t;
        int j = i >> 3, seg = i & 7;
        *reinterpret_cast<uint4*>(&vvsT[j][seg * 8]) = vld0;
        int i2 = t + 256;
        if (i2 < 432) {
            int j2 = i2 >> 3, seg2 = i2 & 7;
            *reinterpret_cast<uint4*>(&vvsT[j2][seg2 * 8]) = vld1;
        }
    }
#pragma unroll
    for (int m = 0; m < 4; m++) {
        int i = t + 256 * m;
        lcs[i >> 6][i & 63] = lld[m];
    }
    __syncthreads();

    // ---- main ----
    int np = t & 31;
    int vgp = t >> 5;

    float acc[4][8];
#pragma unroll
    for (int h = 0; h < 4; h++)
#pragma unroll
        for (int vl = 0; vl < 8; vl++) acc[h][vl] = 0.f;

#pragma unroll
    for (int r = 0; r < Rr; r++) {
        ushort4 g4 = *reinterpret_cast<const ushort4*>(&gsT[r][np][0]);
        uint4 w4 = *reinterpret_cast<const uint4*>(&vvsT[np + r][vgp * 8]);
        float gh[4] = {bf2f(g4.x), bf2f(g4.y), bf2f(g4.z), bf2f(g4.w)};
        float wv[8];
        wv[0] = bflo(w4.x); wv[1] = bfhi(w4.x);
        wv[2] = bflo(w4.y); wv[3] = bfhi(w4.y);
        wv[4] = bflo(w4.z); wv[5] = bfhi(w4.z);
        wv[6] = bflo(w4.w); wv[7] = bfhi(w4.w);
#pragma unroll
        for (int h = 0; h < 4; h++)
#pragma unroll
            for (int vl = 0; vl < 8; vl++) acc[h][vl] += gh[h] * wv[vl];
    }

#pragma unroll
    for (int k = 0; k < 16; k++) {
        ushort4 q4 = *reinterpret_cast<const ushort4*>(&qsT[np][k * 4]);
        float qh[4] = {bf2f(q4.x), bf2f(q4.y), bf2f(q4.z), bf2f(q4.w)};
        const float4* lr = reinterpret_cast<const float4*>(&lcs[k][vgp * 8]);
        float4 la = lr[0], lb = lr[1];
        float lv[8] = {la.x, la.y, la.z, la.w, lb.x, lb.y, lb.z, lb.w};
#pragma unroll
        for (int h = 0; h < 4; h++)
#pragma unroll
            for (int vl = 0; vl < 8; vl++) acc[h][vl] += qh[h] * lv[vl];
    }

    float* ob = out + (size_t)b * 256 * Nn + n0 + np;
#pragma unroll
    for (int h = 0; h < 4; h++)
#pragma unroll
        for (int vl = 0; vl < 8; vl++)
            ob[(size_t)(h * 64 + vgp * 8 + vl) * Nn] = acc[h][vl];
}

extern "C" void kernel_launch(void* const* d_in, const int* in_sizes, int n_in,
                              void* d_out, int out_size, void* d_ws, size_t ws_size,
                              hipStream_t stream) {
    const float* x      = (const float*)d_in[0];
    const float* Wq     = (const float*)d_in[1];
    const float* qg     = (const float*)d_in[2];
    const float* qb     = (const float*)d_in[3];
    const float* qm     = (const float*)d_in[4];
    const float* qv     = (const float*)d_in[5];
    const float* Wk     = (const float*)d_in[6];
    const float* Wv     = (const float*)d_in[7];
    const float* vg     = (const float*)d_in[8];
    const float* vb     = (const float*)d_in[9];
    const float* vm     = (const float*)d_in[10];
    const float* vvar   = (const float*)d_in[11];
    const float* conv_w = (const float*)d_in[12];
    const float* conv_b = (const float*)d_in[13];
    float* out = (float*)d_out;

    float* wsf = (float*)d_ws;
    ushort* Wf16  = (ushort*)wsf;                       // 61440 u16 = 30720 f
    float*  bias  = wsf + 30720;                        // 256 f
    float*  kbuf  = wsf + 30976;                        // 16*16*4096 = 1048576 f
    float*  lam   = wsf + 30976 + 1048576;              // 16384 f
    ushort* qbufT = (ushort*)(wsf + 1095936);           // 16*4096*64 u16
    ushort* vbufT = (ushort*)(wsf + 3193088);           // 16*4096*64 u16
    ushort* gbuf  = (ushort*)(wsf + 5290240);           // 16*23*4096*4 u16

    pack_kernel<<<NCH, 256, 0, stream>>>(Wq, qg, qb, qm, qv, Wk, Wv, vg, vb, vm, vvar,
                                         conv_w, Wf16, bias);
    proj_mfma_kernel<<<dim3(Nn / 64, Bn), 256, 0, stream>>>(x, Wf16, bias,
                                                            qbufT, kbuf, vbufT, gbuf);
    softmax_kernel<<<dim3(Kk, Bn), 256, 0, stream>>>(kbuf);
    hipMemsetAsync(lam, 0, (size_t)Bn * Kk * Vv * sizeof(float), stream);
    lamc_kernel<<<dim3(Nn / NCHUNK, Bn), 256, 0, stream>>>(kbuf, vbufT, lam);
    fused_out_kernel<<<dim3(Nn / TN, Bn), 256, 0, stream>>>(qbufT, vbufT, gbuf, lam,
                                                            conv_b, out);
}

// Round 10
// 78.466 us; speedup vs baseline: 1.2249x; 1.0120x over previous
//
#include <hip/hip_runtime.h>
#include <hip/hip_bf16.h>

typedef unsigned int uint;
typedef unsigned short ushort;

// Dims
#define Bn 16
#define Dd 256
#define Nn 4096
#define Hh 4
#define Kk 16
#define Vv 64
#define Rr 23
#define Cc 144   // 64 q + 16 k + 64 v
#define NRT 9    // 144/16 row-tiles

typedef short bf16x8s __attribute__((ext_vector_type(8)));
typedef float f32x4 __attribute__((ext_vector_type(4)));

static __device__ __forceinline__ ushort f2bf(float f) {
    __hip_bfloat16 h = __float2bfloat16(f);
    return __builtin_bit_cast(ushort, h);
}
static __device__ __forceinline__ float bf2f(ushort u) {
    return __uint_as_float(((uint)u) << 16);
}
static __device__ __forceinline__ float bflo(uint u) { return __uint_as_float(u << 16); }
static __device__ __forceinline__ float bfhi(uint u) { return __uint_as_float(u & 0xffff0000u); }

// ---------------- Kernel 1: pack 144 BN-folded rows (bf16, A-fragment order) ----------------
__global__ __launch_bounds__(256) void pack_kernel(
    const float* __restrict__ Wq, const float* __restrict__ qg, const float* __restrict__ qb,
    const float* __restrict__ qm, const float* __restrict__ qv,
    const float* __restrict__ Wk, const float* __restrict__ Wv,
    const float* __restrict__ vg, const float* __restrict__ vb,
    const float* __restrict__ vm, const float* __restrict__ vvar,
    ushort* __restrict__ Wf16, float* __restrict__ bias) {
    int c = blockIdx.x;       // 0..143
    int d = threadIdx.x;      // 0..255
    float scale, bs;
    const float* src;
    if (c < 64) {
        scale = qg[c] * rsqrtf(qv[c] + 1e-5f);
        bs = qb[c] - qm[c] * scale;
        src = Wq + c * Dd;
    } else if (c < 80) {
        scale = 1.f; bs = 0.f;
        src = Wk + (c - 64) * Dd;
    } else {
        int j = c - 80;
        scale = vg[j] * rsqrtf(vvar[j] + 1e-5f);
        bs = vb[j] - vm[j] * scale;
        src = Wv + j * Dd;
    }
    int rt = c >> 4, lm = c & 15;
    int kk = d >> 5, hi = (d >> 3) & 3, j = d & 7;
    Wf16[((rt * 8 + kk) * 64 + hi * 16 + lm) * 8 + j] = f2bf(src[d] * scale);
    if (d == 0) bias[c] = bs;
}

// ---------------- Kernel 2: MFMA projection (R3 structure) -> consumer-layout buffers ----------
// NRT=9, 2 W-phases, direct coalesced global x loads per kstep. 36.9KB LDS -> 4 blocks/CU.
// Epilogue: kbuf direct; q/v transposed via Wlds then coalesced uint4 stores.
__global__ __launch_bounds__(256, 4) void proj_mfma_kernel(
    const float* __restrict__ x, const ushort* __restrict__ Wf16,
    const float* __restrict__ bias,
    ushort* __restrict__ qbufT, float* __restrict__ kbuf,
    ushort* __restrict__ vbufT) {
    __shared__ ushort Wlds[NRT * 4 * 64 * 8];   // 36864 B

    int b = blockIdx.y;
    int n0 = blockIdx.x * 64;
    int t = threadIdx.x;
    int w = t >> 6, l = t & 63;
    int lm = l & 15, hi = l >> 4;
    int n = n0 + w * 16 + lm;     // this lane's output column

    const uint* WfU = (const uint*)Wf16;
    uint* WldsU = (uint*)Wlds;

    f32x4 acc[NRT];
#pragma unroll
    for (int rt = 0; rt < NRT; rt++) acc[rt] = (f32x4){0.f, 0.f, 0.f, 0.f};

    const float* xb = x + (size_t)b * Dd * Nn + n;

#pragma unroll
    for (int p = 0; p < 2; p++) {
        int kb = p * 4;
        if (p) __syncthreads();
#pragma unroll
        for (int i = 0; i < 36; i++) {
            int flat = t + 256 * i;
            int f2 = flat >> 8;        // rt*4 + kkl
            int rt = f2 >> 2, kkl = f2 & 3;
            WldsU[flat] = WfU[((rt * 8 + kb + kkl) << 8) + (flat & 255)];
        }
        __syncthreads();

#pragma unroll
        for (int kkl = 0; kkl < 4; kkl++) {
            int kk = kb + kkl;
            const float* xp = xb + (size_t)(kk * 32 + hi * 8) * Nn;
            float f[8];
#pragma unroll
            for (int j = 0; j < 8; j++) f[j] = xp[(size_t)j * Nn];
            bf16x8s bfrag;
#pragma unroll
            for (int j = 0; j < 8; j++) bfrag[j] = (short)f2bf(f[j]);
#pragma unroll
            for (int rt = 0; rt < NRT; rt++) {
                bf16x8s afrag = *reinterpret_cast<const bf16x8s*>(
                    &Wlds[(size_t)((rt * 4 + kkl) * 64 + l) * 8]);
                acc[rt] = __builtin_amdgcn_mfma_f32_16x16x32_bf16(afrag, bfrag, acc[rt], 0, 0, 0);
            }
        }
    }

    // ---- epilogue ----
    // kbuf (rows 64..79 = rt 4): channel-major, already coalesced -> direct store
#pragma unroll
    for (int rr = 0; rr < 4; rr++) {
        int kc = hi * 4 + rr;
        kbuf[((size_t)b * 16 + kc) * Nn + n] = acc[4][rr] + bias[64 + kc];
    }

    __syncthreads();   // done reading Wlds; reuse as transpose buffer
    // LDS layout (ushort offsets): q = nl*72 + k*4 + h (64 rows x 72), v = 4608 + nl*72 + v
    {
        int nl = w * 16 + lm;
        // q rows 0..63: k = hi*4+rr, h = rt
#pragma unroll
        for (int rt = 0; rt < 4; rt++)
#pragma unroll
            for (int rr = 0; rr < 4; rr++) {
                int kq = hi * 4 + rr;
                Wlds[nl * 72 + kq * 4 + rt] = f2bf(acc[rt][rr] + bias[rt * 16 + kq]);
            }
        // v rows 80..143 (rt 5..8)
#pragma unroll
        for (int rt = 5; rt < 9; rt++)
#pragma unroll
            for (int rr = 0; rr < 4; rr++) {
                int v = (rt - 5) * 16 + hi * 4 + rr;
                Wlds[4608 + nl * 72 + v] = f2bf(acc[rt][rr] + bias[80 + v]);
            }
    }
    __syncthreads();

    // ---- coalesced stores from LDS ----
#pragma unroll
    for (int m = 0; m < 2; m++) {
        int i = t + 256 * m;
        int row = i >> 3, seg = i & 7;
        uint4 u = *reinterpret_cast<const uint4*>(&Wlds[row * 72 + seg * 8]);
        *reinterpret_cast<uint4*>(&qbufT[((size_t)b * Nn + n0 + row) * 64 + seg * 8]) = u;
    }
#pragma unroll
    for (int m = 0; m < 2; m++) {
        int i = t + 256 * m;
        int row = i >> 3, seg = i & 7;
        uint4 u = *reinterpret_cast<const uint4*>(&Wlds[4608 + row * 72 + seg * 8]);
        *reinterpret_cast<uint4*>(&vbufT[((size_t)b * Nn + n0 + row) * 64 + seg * 8]) = u;
    }
}

// ---------------- Kernel 3: softmax over n for k channels (kbuf) ----------------
__global__ __launch_bounds__(256) void softmax_kernel(float* __restrict__ kbuf) {
    int b = blockIdx.y, kc = blockIdx.x;
    float* row = kbuf + ((size_t)b * 16 + kc) * Nn;
    int t = threadIdx.x;
    float vals[16];
    float m = -1e30f;
#pragma unroll
    for (int i = 0; i < 16; i++) {
        vals[i] = row[t + 256 * i];
        m = fmaxf(m, vals[i]);
    }
#pragma unroll
    for (int off = 32; off; off >>= 1) m = fmaxf(m, __shfl_xor(m, off));
    __shared__ float sm[4], ss[4];
    int wave = t >> 6;
    if ((t & 63) == 0) sm[wave] = m;
    __syncthreads();
    m = fmaxf(fmaxf(sm[0], sm[1]), fmaxf(sm[2], sm[3]));
    float s = 0.f;
#pragma unroll
    for (int i = 0; i < 16; i++) {
        vals[i] = __expf(vals[i] - m);
        s += vals[i];
    }
#pragma unroll
    for (int off = 32; off; off >>= 1) s += __shfl_xor(s, off);
    if ((t & 63) == 0) ss[wave] = s;
    __syncthreads();
    s = ss[0] + ss[1] + ss[2] + ss[3];
    float inv = 1.f / s;
#pragma unroll
    for (int i = 0; i < 16; i++) row[t + 256 * i] = vals[i] * inv;
}

// ---------------- Kernel 4: lam_c[b][16][64] = sum_n kk*vv ----------------
#define NCHUNK 128
__global__ __launch_bounds__(256) void lamc_kernel(
    const float* __restrict__ kbuf, const ushort* __restrict__ vbufT,
    float* __restrict__ lam) {
    int b = blockIdx.y;
    int n0 = blockIdx.x * NCHUNK;
    __shared__ float kks[Kk][NCHUNK + 1];   // 8256 B
    __shared__ ushort vvT[NCHUNK][72];      // 18432 B, rows 144 B
    int t = threadIdx.x;
#pragma unroll
    for (int m = 0; m < 2; m++) {
        int i = t + 256 * m;
        int r = i >> 5, seg = i & 31;
        float4 f = *reinterpret_cast<const float4*>(&kbuf[((size_t)b * 16 + r) * Nn + n0 + seg * 4]);
        kks[r][seg * 4 + 0] = f.x;
        kks[r][seg * 4 + 1] = f.y;
        kks[r][seg * 4 + 2] = f.z;
        kks[r][seg * 4 + 3] = f.w;
    }
#pragma unroll
    for (int m = 0; m < 4; m++) {
        int i = t + 256 * m;
        int row = i >> 3, seg = i & 7;
        uint4 u = *reinterpret_cast<const uint4*>(&vbufT[((size_t)b * Nn + n0 + row) * 64 + seg * 8]);
        *reinterpret_cast<uint4*>(&vvT[row][seg * 8]) = u;
    }
    __syncthreads();
    int v = t & 63, k0 = t >> 6;
    float acc4[4] = {0.f, 0.f, 0.f, 0.f};
    for (int nl = 0; nl < NCHUNK; nl++) {
        float wv = bf2f(vvT[nl][v]);
#pragma unroll
        for (int j2 = 0; j2 < 4; j2++) acc4[j2] += kks[k0 + 4 * j2][nl] * wv;
    }
#pragma unroll
    for (int j2 = 0; j2 < 4; j2++)
        atomicAdd(&lam[((size_t)b * Kk + k0 + 4 * j2) * Vv + v], acc4[j2]);
}

// ---------------- Kernel 5: fused position-lambda + apply ----------------
// TN=32, 256 threads = (vgp 0..7)x(np 0..31); acc[4 h][8 v]. Linear staging + in-kernel g-phase.
#define TN 32
__global__ __launch_bounds__(256, 6) void fused_out_kernel(
    const ushort* __restrict__ qbufT, const ushort* __restrict__ vbufT,
    const float* __restrict__ lam, const float* __restrict__ conv_w,
    const float* __restrict__ conv_b, float* __restrict__ out) {
    __shared__ ushort vvsT[54][72];       // [j][v] bf16; n = n0-11+j; rows 144 B
    __shared__ ushort qsT[TN][68];        // [np][k*4+h] bf16; rows 136 B
    __shared__ ushort gsT[Rr][TN][4];     // [r][np][h] bf16 (computed in-kernel)
    __shared__ float  lcs[Kk][Vv];        // lam_c + conv_b
    __shared__ float  cwsT[Rr][16];       // conv_w transposed [r][k]

    int b = blockIdx.y;
    int n0 = blockIdx.x * TN;
    int t = threadIdx.x;

    // ---- load phase (all globals issued before any LDS write) ----
    uint2 qld0, qld1;
    {
        int i = t;
        int np = i >> 4, seg = i & 15;
        qld0 = *reinterpret_cast<const uint2*>(&qbufT[((size_t)b * Nn + n0 + np) * 64 + seg * 4]);
        int i2 = t + 256;
        int np2 = i2 >> 4, seg2 = i2 & 15;
        qld1 = *reinterpret_cast<const uint2*>(&qbufT[((size_t)b * Nn + n0 + np2) * 64 + seg2 * 4]);
    }
    uint4 vld0 = {0, 0, 0, 0}, vld1 = {0, 0, 0, 0};
    {
        int i = t;
        int j = i >> 3, seg = i & 7;
        int nn = n0 - 11 + j;
        if (nn >= 0 && nn < Nn)
            vld0 = *reinterpret_cast<const uint4*>(&vbufT[((size_t)b * Nn + nn) * 64 + seg * 8]);
        int i2 = t + 256;
        int j2 = i2 >> 3, seg2 = i2 & 7;
        int nn2 = n0 - 11 + j2;
        if (i2 < 432 && nn2 >= 0 && nn2 < Nn)
            vld1 = *reinterpret_cast<const uint4*>(&vbufT[((size_t)b * Nn + nn2) * 64 + seg2 * 8]);
    }
    float lld[4];
#pragma unroll
    for (int m = 0; m < 4; m++) {
        int i = t + 256 * m;
        lld[m] = lam[(size_t)b * Kk * Vv + i] + conv_b[i >> 6];
    }
    float cw0 = 0.f, cw1 = 0.f;
    {
        // cwsT[r][k] = conv_w[k*23+r]; 368 elements
        int i = t;
        if (i < 368) cw0 = conv_w[(i & 15) * Rr + (i >> 4)];
        int i2 = t + 256;
        if (i2 < 368) cw1 = conv_w[(i2 & 15) * Rr + (i2 >> 4)];
    }

    // ---- write phase ----
    {
        int i = t;
        int np = i >> 4, seg = i & 15;
        *reinterpret_cast<uint2*>(&qsT[np][seg * 4]) = qld0;
        int i2 = t + 256;
        int np2 = i2 >> 4, seg2 = i2 & 15;
        *reinterpret_cast<uint2*>(&qsT[np2][seg2 * 4]) = qld1;
    }
    {
        int i = t;
        int j = i >> 3, seg = i & 7;
        *reinterpret_cast<uint4*>(&vvsT[j][seg * 8]) = vld0;
        int i2 = t + 256;
        if (i2 < 432) {
            int j2 = i2 >> 3, seg2 = i2 & 7;
            *reinterpret_cast<uint4*>(&vvsT[j2][seg2 * 8]) = vld1;
        }
    }
#pragma unroll
    for (int m = 0; m < 4; m++) {
        int i = t + 256 * m;
        lcs[i >> 6][i & 63] = lld[m];
    }
    {
        int i = t;
        if (i < 368) cwsT[i >> 4][i & 15] = cw0;
        int i2 = t + 256;
        if (i2 < 368) cwsT[i2 >> 4][i2 & 15] = cw1;
    }
    __syncthreads();

    // ---- g phase: all 256 threads; thread = (rh, h, nl); r split 0..11 / 12..22 ----
    {
        int rh = t >> 7;          // 0: r 0..11, 1: r 12..22
        int h = (t >> 5) & 3;
        int nl = t & 31;
        float qreg[16];
#pragma unroll
        for (int k = 0; k < 16; k++) qreg[k] = bf2f(qsT[nl][k * 4 + h]);
#pragma unroll
        for (int i = 0; i < 12; i++) {
            int r = rh * 12 + i;
            if (r < 23) {
                const float4* cr = reinterpret_cast<const float4*>(&cwsT[r][0]);
                float4 c0 = cr[0], c1 = cr[1], c2 = cr[2], c3 = cr[3];
                float g = qreg[0] * c0.x + qreg[1] * c0.y + qreg[2] * c0.z + qreg[3] * c0.w
                        + qreg[4] * c1.x + qreg[5] * c1.y + qreg[6] * c1.z + qreg[7] * c1.w
                        + qreg[8] * c2.x + qreg[9] * c2.y + qreg[10] * c2.z + qreg[11] * c2.w
                        + qreg[12] * c3.x + qreg[13] * c3.y + qreg[14] * c3.z + qreg[15] * c3.w;
                gsT[r][nl][h] = f2bf(g);
            }
        }
    }
    __syncthreads();

    // ---- main ----
    int np = t & 31;
    int vgp = t >> 5;

    float acc[4][8];
#pragma unroll
    for (int h = 0; h < 4; h++)
#pragma unroll
        for (int vl = 0; vl < 8; vl++) acc[h][vl] = 0.f;

#pragma unroll
    for (int r = 0; r < Rr; r++) {
        ushort4 g4 = *reinterpret_cast<const ushort4*>(&gsT[r][np][0]);
        uint4 w4 = *reinterpret_cast<const uint4*>(&vvsT[np + r][vgp * 8]);
        float gh[4] = {bf2f(g4.x), bf2f(g4.y), bf2f(g4.z), bf2f(g4.w)};
        float wv[8];
        wv[0] = bflo(w4.x); wv[1] = bfhi(w4.x);
        wv[2] = bflo(w4.y); wv[3] = bfhi(w4.y);
        wv[4] = bflo(w4.z); wv[5] = bfhi(w4.z);
        wv[6] = bflo(w4.w); wv[7] = bfhi(w4.w);
#pragma unroll
        for (int h = 0; h < 4; h++)
#pragma unroll
            for (int vl = 0; vl < 8; vl++) acc[h][vl] += gh[h] * wv[vl];
    }

#pragma unroll
    for (int k = 0; k < 16; k++) {
        ushort4 q4 = *reinterpret_cast<const ushort4*>(&qsT[np][k * 4]);
        float qh[4] = {bf2f(q4.x), bf2f(q4.y), bf2f(q4.z), bf2f(q4.w)};
        const float4* lr = reinterpret_cast<const float4*>(&lcs[k][vgp * 8]);
        float4 la = lr[0], lb = lr[1];
        float lv[8] = {la.x, la.y, la.z, la.w, lb.x, lb.y, lb.z, lb.w};
#pragma unroll
        for (int h = 0; h < 4; h++)
#pragma unroll
            for (int vl = 0; vl < 8; vl++) acc[h][vl] += qh[h] * lv[vl];
    }

    float* ob = out + (size_t)b * 256 * Nn + n0 + np;
#pragma unroll
    for (int h = 0; h < 4; h++)
#pragma unroll
        for (int vl = 0; vl < 8; vl++)
            ob[(size_t)(h * 64 + vgp * 8 + vl) * Nn] = acc[h][vl];
}

extern "C" void kernel_launch(void* const* d_in, const int* in_sizes, int n_in,
                              void* d_out, int out_size, void* d_ws, size_t ws_size,
                              hipStream_t stream) {
    const float* x      = (const float*)d_in[0];
    const float* Wq     = (const float*)d_in[1];
    const float* qg     = (const float*)d_in[2];
    const float* qb     = (const float*)d_in[3];
    const float* qm     = (const float*)d_in[4];
    const float* qv     = (const float*)d_in[5];
    const float* Wk     = (const float*)d_in[6];
    const float* Wv     = (const float*)d_in[7];
    const float* vg     = (const float*)d_in[8];
    const float* vb     = (const float*)d_in[9];
    const float* vm     = (const float*)d_in[10];
    const float* vvar   = (const float*)d_in[11];
    const float* conv_w = (const float*)d_in[12];
    const float* conv_b = (const float*)d_in[13];
    float* out = (float*)d_out;

    float* wsf = (float*)d_ws;
    ushort* Wf16  = (ushort*)wsf;                       // 36864 u16 = 18432 f
    float*  bias  = wsf + 18432;                        // 256 f
    float*  kbuf  = wsf + 18688;                        // 16*16*4096 = 1048576 f
    float*  lam   = wsf + 18688 + 1048576;              // 16384 f
    ushort* qbufT = (ushort*)(wsf + 1083648);           // 16*4096*64 u16 = 2097152 f
    ushort* vbufT = (ushort*)(wsf + 3180800);           // 16*4096*64 u16

    pack_kernel<<<Cc, 256, 0, stream>>>(Wq, qg, qb, qm, qv, Wk, Wv, vg, vb, vm, vvar,
                                        Wf16, bias);
    proj_mfma_kernel<<<dim3(Nn / 64, Bn), 256, 0, stream>>>(x, Wf16, bias,
                                                            qbufT, kbuf, vbufT);
    softmax_kernel<<<dim3(Kk, Bn), 256, 0, stream>>>(kbuf);
    hipMemsetAsync(lam, 0, (size_t)Bn * Kk * Vv * sizeof(float), stream);
    lamc_kernel<<<dim3(Nn / NCHUNK, Bn), 256, 0, stream>>>(kbuf, vbufT, lam);
    fused_out_kernel<<<dim3(Nn / TN, Bn), 256, 0, stream>>>(qbufT, vbufT, lam,
                                                            conv_w, conv_b, out);
}